// Round 2
// baseline (377.178 us; speedup 1.0000x reference)
//
#include <hip/hip_runtime.h>
#include <cstdint>
#include <cstddef>

// NOBlock: B=4, N=2048, V=1, M=64 (8x8), C=128, rank 8, GRP=4.
// One block = one output group (4 consecutive tokens). 256 threads.
//
// Pipeline per block:
//   for each of 4 tokens:
//     stage x tile into LDS (padded rows, stride 132 to avoid bank conflicts)
//     acc += x                    (residual folded in; x read exactly once)
//     t1[m,F]   = sum_e x[m,e] * in_f2[e,F]          (C -> rank)
//     t2[a,E,F] = sum_d t1[a,d,F] * in_f1[d,E]
//     z[D,E,F]  = sum_a t2[a,E,F] * in_f0[a,D]       -> zall[tok]
//   stage C (ONCE, 4-token reuse of the 1MB core):
//     z2[tok][ABC] = sum_DEF core[ABC,DEF] * zall[tok][DEF]
//   for each token:
//     u[o,B,Cr] = sum_A z2[A,B,Cr] * out_f0[o,A]
//     v[o,p,Cr] = sum_B u[o,B,Cr]  * out_f1[p,B]
//     acc      += sum_Cr v[m,Cr]   * out_f2[q,Cr]    (q fixed per thread)
//   out = acc * winv[m]   (winv = 1/count_unmasked, 0 if all masked)
//
// mask is a bool array in the reference -> pushed as int32 by the harness.

__launch_bounds__(256, 2)
__global__ void noblock_kernel(const float* __restrict__ x,
                               const float* __restrict__ core,
                               const float* __restrict__ of0,
                               const float* __restrict__ of1,
                               const float* __restrict__ of2,
                               const float* __restrict__ if0,
                               const float* __restrict__ if1,
                               const float* __restrict__ if2,
                               const int* __restrict__ mask,
                               float* __restrict__ out)
{
    __shared__ float xs[64 * 132];      // 33.8 KB padded token tile
    __shared__ float t1[512];
    __shared__ float t2[512];
    __shared__ float zall[4 * 512];
    __shared__ float z2all[4 * 512];
    __shared__ float s_if2[1024];
    __shared__ float s_of2[1024];
    __shared__ float s_if0[64], s_if1[64], s_of0[64], s_of1[64];
    __shared__ float winv[64];

    const int t = threadIdx.x;
    const int blk = blockIdx.x;                    // b*512 + g
    const long tok0 = (long)(blk >> 9) * 2048 + (long)(blk & 511) * 4;

    // stage factor matrices + per-cell inverse weights
    for (int i = t; i < 1024; i += 256) { s_if2[i] = if2[i]; s_of2[i] = of2[i]; }
    if (t < 64) {
        s_if0[t] = if0[t]; s_if1[t] = if1[t]; s_of0[t] = of0[t]; s_of1[t] = of1[t];
        const int* mp = mask + (size_t)tok0 * 64 + t;   // int32 mask elements
        int cnt = 0;
        #pragma unroll
        for (int j = 0; j < 4; ++j) cnt += (mp[j * 64] == 0) ? 1 : 0;
        winv[t] = (cnt > 0) ? 1.0f / (float)cnt : 0.0f;
    }

    float acc[32];
    #pragma unroll
    for (int k = 0; k < 32; ++k) acc[k] = 0.0f;

    __syncthreads();

    // per-thread out_f2 row: with f = t + 256k, q = f & 127 = t & 127 (fixed)
    float myof2[8];
    {
        const int q = t & 127;
        #pragma unroll
        for (int r = 0; r < 8; ++r) myof2[r] = s_of2[q * 8 + r];
    }

    // ---- per-token: stage, residual, project to rank space ----
    for (int j = 0; j < 4; ++j) {
        const float4* xg = (const float4*)(x + (tok0 + j) * 8192);
        #pragma unroll
        for (int i = 0; i < 8; ++i) {
            const int f4 = t + i * 256;
            const float4 v = xg[f4];
            const int f = f4 * 4;
            *(float4*)&xs[(f >> 7) * 132 + (f & 127)] = v;
        }
        __syncthreads();

        // residual accumulate (bank-spread by pad: 2-way max, free)
        #pragma unroll
        for (int k = 0; k < 32; ++k) {
            const int f = t + k * 256;
            acc[k] += xs[(f >> 7) * 132 + (f & 127)];
        }

        // stage A: t1[m*8+F] = sum_e xs[m][e] * if2[e][F]
        #pragma unroll
        for (int h = 0; h < 2; ++h) {
            const int id = t + h * 256;
            const int m = id >> 3, F = id & 7;
            const float* xr = &xs[m * 132];
            float s = 0.0f;
            #pragma unroll 8
            for (int e = 0; e < 128; ++e) s = fmaf(xr[e], s_if2[e * 8 + F], s);
            t1[id] = s;
        }
        __syncthreads();

        // stage B1: t2[a*64+E*8+F] = sum_d t1[a*64+d*8+F] * if1[d][E]
        #pragma unroll
        for (int h = 0; h < 2; ++h) {
            const int id = t + h * 256;
            const int a = id >> 6, E = (id >> 3) & 7, F = id & 7;
            float s = 0.0f;
            #pragma unroll
            for (int d = 0; d < 8; ++d) s = fmaf(t1[a * 64 + d * 8 + F], s_if1[d * 8 + E], s);
            t2[id] = s;
        }
        __syncthreads();

        // stage B2: z[D*64+E*8+F] = sum_a t2[a*64+E*8+F] * if0[a][D]
        #pragma unroll
        for (int h = 0; h < 2; ++h) {
            const int id = t + h * 256;
            const int D = id >> 6, E = (id >> 3) & 7, F = id & 7;
            float s = 0.0f;
            #pragma unroll
            for (int a = 0; a < 8; ++a) s = fmaf(t2[a * 64 + E * 8 + F], s_if0[a * 8 + D], s);
            zall[j * 512 + id] = s;
        }
        __syncthreads();
    }

    // ---- stage C: core contraction, ONE pass over core for all 4 tokens ----
    {
        float a0[4] = {0, 0, 0, 0}, a1[4] = {0, 0, 0, 0};
        const float4* cr0 = (const float4*)(core + (size_t)t * 512);
        const float4* cr1 = (const float4*)(core + (size_t)(t + 256) * 512);
        const float4* z4 = (const float4*)zall;
        for (int kk = 0; kk < 128; ++kk) {
            const float4 c0 = cr0[kk];
            const float4 c1 = cr1[kk];
            #pragma unroll
            for (int j = 0; j < 4; ++j) {
                const float4 zv = z4[j * 128 + kk];   // broadcast read
                a0[j] = fmaf(c0.x, zv.x, fmaf(c0.y, zv.y, fmaf(c0.z, zv.z, fmaf(c0.w, zv.w, a0[j]))));
                a1[j] = fmaf(c1.x, zv.x, fmaf(c1.y, zv.y, fmaf(c1.z, zv.z, fmaf(c1.w, zv.w, a1[j]))));
            }
        }
        #pragma unroll
        for (int j = 0; j < 4; ++j) {
            z2all[j * 512 + t]       = a0[j];
            z2all[j * 512 + t + 256] = a1[j];
        }
    }
    __syncthreads();

    // ---- stage D per token: expand + accumulate ----
    for (int j = 0; j < 4; ++j) {
        // D1: u[o*64+B*8+Cr] = sum_A z2[A*64+B*8+Cr] * of0[o][A]   (into t1)
        #pragma unroll
        for (int h = 0; h < 2; ++h) {
            const int id = t + h * 256;
            const int o = id >> 6, Bq = (id >> 3) & 7, Cr = id & 7;
            float s = 0.0f;
            #pragma unroll
            for (int A = 0; A < 8; ++A)
                s = fmaf(z2all[j * 512 + A * 64 + Bq * 8 + Cr], s_of0[o * 8 + A], s);
            t1[id] = s;
        }
        __syncthreads();
        // D2: v[o*64+p*8+Cr] = sum_B u[o*64+B*8+Cr] * of1[p][B]    (into t2)
        #pragma unroll
        for (int h = 0; h < 2; ++h) {
            const int id = t + h * 256;
            const int o = id >> 6, p = (id >> 3) & 7, Cr = id & 7;
            float s = 0.0f;
            #pragma unroll
            for (int Bq = 0; Bq < 8; ++Bq)
                s = fmaf(t1[o * 64 + Bq * 8 + Cr], s_of1[p * 8 + Bq], s);
            t2[id] = s;
        }
        __syncthreads();
        // D3: acc += sum_Cr v[m*8+Cr] * of2[q][Cr]  (m = (t>>7)+2k, broadcast reads)
        #pragma unroll
        for (int k = 0; k < 32; ++k) {
            const int m = (t >> 7) + 2 * k;
            float s = 0.0f;
            #pragma unroll
            for (int r = 0; r < 8; ++r) s = fmaf(t2[m * 8 + r], myof2[r], s);
            acc[k] += s;
        }
        __syncthreads();
    }

    // ---- final: divide by unmasked count, write ----
    const size_t obase = (size_t)blk * 8192;
    #pragma unroll
    for (int k = 0; k < 32; ++k) {
        const int f = t + k * 256;
        out[obase + f] = acc[k] * winv[f >> 7];
    }
}

extern "C" void kernel_launch(void* const* d_in, const int* in_sizes, int n_in,
                              void* d_out, int out_size, void* d_ws, size_t ws_size,
                              hipStream_t stream) {
    const float* x    = (const float*)d_in[0];
    const float* core = (const float*)d_in[1];
    const float* of0  = (const float*)d_in[2];
    const float* of1  = (const float*)d_in[3];
    const float* of2  = (const float*)d_in[4];
    const float* if0  = (const float*)d_in[5];
    const float* if1  = (const float*)d_in[6];
    const float* if2  = (const float*)d_in[7];
    const int* mask   = (const int*)d_in[8];
    float* out = (float*)d_out;

    noblock_kernel<<<dim3(2048), dim3(256), 0, stream>>>(
        x, core, of0, of1, of2, if0, if1, if2, mask, out);
}

// Round 3
// 375.700 us; speedup vs baseline: 1.0039x; 1.0039x over previous
//
#include <hip/hip_runtime.h>
#include <cstdint>
#include <cstddef>

// NOBlock: B=4, N=2048, V=1, M=64 (8x8), C=128, rank 8, GRP=4.
// One block = one output group (4 consecutive tokens). 256 threads.
//
// Pipeline per block:
//   for each of 4 tokens:
//     stage x tile into LDS (padded rows, stride 132 to avoid bank conflicts)
//     acc += x                    (residual folded in; x read exactly once)
//     t1[m,F]   = sum_e x[m,e] * in_f2[e,F]          (C -> rank)
//     t2[a,E,F] = sum_d t1[a,d,F] * in_f1[d,E]
//     z[D,E,F]  = sum_a t2[a,E,F] * in_f0[a,D]       -> zall[tok]
//   stage C (ONCE, 4-token reuse of the 1MB core):
//     z2[tok][ABC] = sum_DEF core[ABC,DEF] * zall[tok][DEF]
//   for each token:
//     u[o,B,Cr] = sum_A z2[A,B,Cr] * out_f0[o,A]
//     v[o,p,Cr] = sum_B u[o,B,Cr]  * out_f1[p,B]
//     acc      += sum_Cr v[m,Cr]   * out_f2[q,Cr]    (q fixed per thread)
//   out = acc * winv[m]   (winv = 1/count_unmasked, 0 if all masked)
//
// mask is a bool array in the reference -> pushed as int32 by the harness.

__launch_bounds__(256, 2)
__global__ void noblock_kernel(const float* __restrict__ x,
                               const float* __restrict__ core,
                               const float* __restrict__ of0,
                               const float* __restrict__ of1,
                               const float* __restrict__ of2,
                               const float* __restrict__ if0,
                               const float* __restrict__ if1,
                               const float* __restrict__ if2,
                               const int* __restrict__ mask,
                               float* __restrict__ out)
{
    __shared__ float xs[64 * 132];      // 33.8 KB padded token tile
    __shared__ float t1[512];
    __shared__ float t2[512];
    __shared__ float zall[4 * 512];
    __shared__ float z2all[4 * 512];
    __shared__ float s_if2[1024];
    __shared__ float s_of2[1024];
    __shared__ float s_if0[64], s_if1[64], s_of0[64], s_of1[64];
    __shared__ float winv[64];

    const int t = threadIdx.x;
    const int blk = blockIdx.x;                    // b*512 + g
    const long tok0 = (long)(blk >> 9) * 2048 + (long)(blk & 511) * 4;

    // stage factor matrices + per-cell inverse weights
    for (int i = t; i < 1024; i += 256) { s_if2[i] = if2[i]; s_of2[i] = of2[i]; }
    if (t < 64) {
        s_if0[t] = if0[t]; s_if1[t] = if1[t]; s_of0[t] = of0[t]; s_of1[t] = of1[t];
        const int* mp = mask + (size_t)tok0 * 64 + t;   // int32 mask elements
        int cnt = 0;
        #pragma unroll
        for (int j = 0; j < 4; ++j) cnt += (mp[j * 64] == 0) ? 1 : 0;
        winv[t] = (cnt > 0) ? 1.0f / (float)cnt : 0.0f;
    }

    float acc[32];
    #pragma unroll
    for (int k = 0; k < 32; ++k) acc[k] = 0.0f;

    __syncthreads();

    // per-thread out_f2 row: with f = t + 256k, q = f & 127 = t & 127 (fixed)
    float myof2[8];
    {
        const int q = t & 127;
        #pragma unroll
        for (int r = 0; r < 8; ++r) myof2[r] = s_of2[q * 8 + r];
    }

    // ---- per-token: stage, residual, project to rank space ----
    for (int j = 0; j < 4; ++j) {
        const float4* xg = (const float4*)(x + (tok0 + j) * 8192);
        #pragma unroll
        for (int i = 0; i < 8; ++i) {
            const int f4 = t + i * 256;
            const float4 v = xg[f4];
            const int f = f4 * 4;
            *(float4*)&xs[(f >> 7) * 132 + (f & 127)] = v;
        }
        __syncthreads();

        // residual accumulate (bank-spread by pad: 2-way max, free)
        #pragma unroll
        for (int k = 0; k < 32; ++k) {
            const int f = t + k * 256;
            acc[k] += xs[(f >> 7) * 132 + (f & 127)];
        }

        // stage A: t1[m*8+F] = sum_e xs[m][e] * if2[e][F]
        #pragma unroll
        for (int h = 0; h < 2; ++h) {
            const int id = t + h * 256;
            const int m = id >> 3, F = id & 7;
            const float* xr = &xs[m * 132];
            float s = 0.0f;
            #pragma unroll 8
            for (int e = 0; e < 128; ++e) s = fmaf(xr[e], s_if2[e * 8 + F], s);
            t1[id] = s;
        }
        __syncthreads();

        // stage B1: t2[a*64+E*8+F] = sum_d t1[a*64+d*8+F] * if1[d][E]
        #pragma unroll
        for (int h = 0; h < 2; ++h) {
            const int id = t + h * 256;
            const int a = id >> 6, E = (id >> 3) & 7, F = id & 7;
            float s = 0.0f;
            #pragma unroll
            for (int d = 0; d < 8; ++d) s = fmaf(t1[a * 64 + d * 8 + F], s_if1[d * 8 + E], s);
            t2[id] = s;
        }
        __syncthreads();

        // stage B2: z[D*64+E*8+F] = sum_a t2[a*64+E*8+F] * if0[a][D]
        #pragma unroll
        for (int h = 0; h < 2; ++h) {
            const int id = t + h * 256;
            const int D = id >> 6, E = (id >> 3) & 7, F = id & 7;
            float s = 0.0f;
            #pragma unroll
            for (int a = 0; a < 8; ++a) s = fmaf(t2[a * 64 + E * 8 + F], s_if0[a * 8 + D], s);
            zall[j * 512 + id] = s;
        }
        __syncthreads();
    }

    // ---- stage C: core contraction, ONE pass over core for all 4 tokens ----
    {
        float a0[4] = {0, 0, 0, 0}, a1[4] = {0, 0, 0, 0};
        const float4* cr0 = (const float4*)(core + (size_t)t * 512);
        const float4* cr1 = (const float4*)(core + (size_t)(t + 256) * 512);
        const float4* z4 = (const float4*)zall;
        for (int kk = 0; kk < 128; ++kk) {
            const float4 c0 = cr0[kk];
            const float4 c1 = cr1[kk];
            #pragma unroll
            for (int j = 0; j < 4; ++j) {
                const float4 zv = z4[j * 128 + kk];   // broadcast read
                a0[j] = fmaf(c0.x, zv.x, fmaf(c0.y, zv.y, fmaf(c0.z, zv.z, fmaf(c0.w, zv.w, a0[j]))));
                a1[j] = fmaf(c1.x, zv.x, fmaf(c1.y, zv.y, fmaf(c1.z, zv.z, fmaf(c1.w, zv.w, a1[j]))));
            }
        }
        #pragma unroll
        for (int j = 0; j < 4; ++j) {
            z2all[j * 512 + t]       = a0[j];
            z2all[j * 512 + t + 256] = a1[j];
        }
    }
    __syncthreads();

    // ---- stage D per token: expand + accumulate ----
    for (int j = 0; j < 4; ++j) {
        // D1: u[o*64+B*8+Cr] = sum_A z2[A*64+B*8+Cr] * of0[o][A]   (into t1)
        #pragma unroll
        for (int h = 0; h < 2; ++h) {
            const int id = t + h * 256;
            const int o = id >> 6, Bq = (id >> 3) & 7, Cr = id & 7;
            float s = 0.0f;
            #pragma unroll
            for (int A = 0; A < 8; ++A)
                s = fmaf(z2all[j * 512 + A * 64 + Bq * 8 + Cr], s_of0[o * 8 + A], s);
            t1[id] = s;
        }
        __syncthreads();
        // D2: v[o*64+p*8+Cr] = sum_B u[o*64+B*8+Cr] * of1[p][B]    (into t2)
        #pragma unroll
        for (int h = 0; h < 2; ++h) {
            const int id = t + h * 256;
            const int o = id >> 6, p = (id >> 3) & 7, Cr = id & 7;
            float s = 0.0f;
            #pragma unroll
            for (int Bq = 0; Bq < 8; ++Bq)
                s = fmaf(t1[o * 64 + Bq * 8 + Cr], s_of1[p * 8 + Bq], s);
            t2[id] = s;
        }
        __syncthreads();
        // D3: acc += sum_Cr v[m*8+Cr] * of2[q][Cr]  (m = (t>>7)+2k, broadcast reads)
        #pragma unroll
        for (int k = 0; k < 32; ++k) {
            const int m = (t >> 7) + 2 * k;
            float s = 0.0f;
            #pragma unroll
            for (int r = 0; r < 8; ++r) s = fmaf(t2[m * 8 + r], myof2[r], s);
            acc[k] += s;
        }
        __syncthreads();
    }

    // ---- final: divide by unmasked count, write ----
    const size_t obase = (size_t)blk * 8192;
    #pragma unroll
    for (int k = 0; k < 32; ++k) {
        const int f = t + k * 256;
        out[obase + f] = acc[k] * winv[f >> 7];
    }
}

extern "C" void kernel_launch(void* const* d_in, const int* in_sizes, int n_in,
                              void* d_out, int out_size, void* d_ws, size_t ws_size,
                              hipStream_t stream) {
    const float* x    = (const float*)d_in[0];
    const float* core = (const float*)d_in[1];
    const float* of0  = (const float*)d_in[2];
    const float* of1  = (const float*)d_in[3];
    const float* of2  = (const float*)d_in[4];
    const float* if0  = (const float*)d_in[5];
    const float* if1  = (const float*)d_in[6];
    const float* if2  = (const float*)d_in[7];
    const int* mask   = (const int*)d_in[8];
    float* out = (float*)d_out;

    noblock_kernel<<<dim3(2048), dim3(256), 0, stream>>>(
        x, core, of0, of1, of2, if0, if1, if2, mask, out);
}